// Round 5
// baseline (50.617 us; speedup 1.0000x reference)
//
#include <hip/hip_runtime.h>

// RefinementCAM: B=4, C=256, H=W=64, N=4096.
// out[b,n] = s[b,n] * (feat[b,:,n] . v[b,:]),
//   v[b,c] = sum_m feat[b,c,m] * w[b,m],  w = s*cam,
//   s = m/max(m*||feat[:,n]||,1e-12),  m in {0,1/3,2/3,1}.
// K1: one cold feat pass; tile stashed in padded LDS -> norm + v-partials.
// K2: tiny 512KB partial reduce. K3: out pass (L2-hot feat) + last-block
//     finale (batch minmax, rescale, loss) -- fixed-order, deterministic.

constexpr int B  = 4;
constexpr int C  = 256;
constexpr int N  = 4096;
constexpr int BN = B * N;       // 16384
constexpr int CN = C * N;
constexpr int NBLK = 512;       // K1/K3 blocks (32 pixels each)

__device__ __forceinline__ float wsum(float v) {
#pragma unroll
    for (int o = 32; o > 0; o >>= 1) v += __shfl_down(v, o, 64);
    return v;
}
__device__ __forceinline__ float wmin64(float v) {
#pragma unroll
    for (int o = 32; o > 0; o >>= 1) v = fminf(v, __shfl_down(v, o, 64));
    return v;
}
__device__ __forceinline__ float wmax64(float v) {
#pragma unroll
    for (int o = 32; o > 0; o >>= 1) v = fmaxf(v, __shfl_down(v, o, 64));
    return v;
}

// K1: 512 blocks x 256 thr. Coalesced cold read of the block's 256x32 feat
// tile; square-accumulate into per-pixel norms WHILE stashing values in
// padded LDS; then v_part[c] from LDS (no global re-read). Zeroes cnt.
__global__ void __launch_bounds__(256) k_norm_vpart(
    const float* __restrict__ cam, const float* __restrict__ feat,
    float* __restrict__ s, float* __restrict__ v_part,
    unsigned int* __restrict__ cnt)
{
    if (blockIdx.x == 0 && threadIdx.x == 0) *cnt = 0u;

    __shared__ float tile[C * 33];   // [c][pix] padded: stride 33 floats
    __shared__ float red[8][33];
    __shared__ float w_sh[32];

    const int t   = threadIdx.x;
    const int pix = t & 31;
    const int g   = t >> 5;          // channel group 0..7 (32 channels each)
    const int bk  = blockIdx.x;
    const int b   = bk >> 7;         // 128 blocks per batch
    const int n0  = (bk * 32) & (N - 1);

    // phase 1: cold coalesced read; norm accumulate + LDS stash
    {
        const float* fp = feat + (size_t)b * CN + (size_t)(g * 32) * N + n0 + pix;
        float ss = 0.f;
#pragma unroll
        for (int cc = 0; cc < 32; ++cc) {
            float x = fp[(size_t)cc * N];            // 32-lane contiguous
            ss = fmaf(x, x, ss);
            tile[(g * 32 + cc) * 33 + pix] = x;      // 2-way bank alias: free
        }
        red[g][pix] = ss;
    }
    __syncthreads();
    if (t < 32) {
        float tot = 0.f;
#pragma unroll
        for (int gg = 0; gg < 8; ++gg) tot += red[gg][t];
        float cv = cam[bk * 32 + t];
        float m  = ((cv >= 0.3f ? 1.f : 0.f) + (cv >= 0.4f ? 1.f : 0.f) +
                    (cv >= 0.5f ? 1.f : 0.f)) * (1.f / 3.f);
        float sc = m / fmaxf(m * sqrtf(tot), 1e-12f);  // ||feat*m|| = m*||feat||
        s[bk * 32 + t] = sc;
        w_sh[t] = sc * cv;
    }
    __syncthreads();

    // phase 2: thread = channel; 32 LDS reads (2-way alias), w broadcast
    {
        float acc = 0.f;
#pragma unroll
        for (int pp = 0; pp < 32; ++pp)
            acc = fmaf(tile[t * 33 + pp], w_sh[pp], acc);
        v_part[bk * 256 + t] = acc;                  // coalesced
    }
}

// K2: v[b,c] = sum of the batch's 128 block-partials. 4 blocks x 256 thr.
__global__ void __launch_bounds__(256) k_vreduce(
    const float* __restrict__ v_part, float* __restrict__ v)
{
    const int c = threadIdx.x;
    const int b = blockIdx.x;
    const float* base = v_part + (size_t)b * 128 * 256 + c;
    float acc = 0.f;
#pragma unroll 8
    for (int k = 0; k < 128; ++k) acc += base[k * 256];   // coalesced
    v[b * 256 + c] = acc;
}

// K3: 512 blocks x 256 thr. ob = s*(feat[:,n].v) (feat L2-hot from K1);
// block min/max; LAST block: batch minmax, rescale, loss (fixed order).
__global__ void __launch_bounds__(256) k_out_final(
    const float* __restrict__ feat, const float* __restrict__ s,
    const float* __restrict__ v, const float* __restrict__ cam,
    float* __restrict__ ob, float* __restrict__ bmn, float* __restrict__ bmx,
    float* __restrict__ out, unsigned int* __restrict__ cnt)
{
    const int t   = threadIdx.x;
    const int pix = t & 31;
    const int g   = t >> 5;
    const int bk  = blockIdx.x;
    const int b   = bk >> 7;
    const int n0  = (bk * 32) & (N - 1);

    __shared__ float vs[C];
    vs[t] = v[b * C + t];
    __syncthreads();

    const float* fp = feat + (size_t)b * CN + (size_t)(g * 32) * N + n0 + pix;
    float acc = 0.f;
#pragma unroll 8
    for (int cc = 0; cc < 32; ++cc)
        acc = fmaf(fp[(size_t)cc * N], vs[g * 32 + cc], acc);  // vs broadcast

    __shared__ float red[8][33];
    red[g][pix] = acc;
    __syncthreads();
    if (t < 32) {
        float tot = 0.f;
#pragma unroll
        for (int gg = 0; gg < 8; ++gg) tot += red[gg][t];
        float o = s[bk * 32 + t] * tot;
        ob[bk * 32 + t] = o;
        float mn = o, mx = o;
#pragma unroll
        for (int o2 = 16; o2 > 0; o2 >>= 1) {
            mn = fminf(mn, __shfl_down(mn, o2, 64));
            mx = fmaxf(mx, __shfl_down(mx, o2, 64));
        }
        if (t == 0) { bmn[bk] = mn; bmx[bk] = mx; }
    }

    // ---- last-block finale ----
    __shared__ int lastflag;
    __syncthreads();                 // all stores (ob,bmn,bmx) issued
    if (t == 0) {
        __threadfence();             // agent-scope visibility of plain stores
        unsigned old = __hip_atomic_fetch_add(cnt, 1u, __ATOMIC_ACQ_REL,
                                              __HIP_MEMORY_SCOPE_AGENT);
        lastflag = (old == NBLK - 1u) ? 1 : 0;
    }
    __syncthreads();
    if (!lastflag) return;

    // batch min/max from 128 entries per batch: wave w handles batch w
    __shared__ float shmn[4], shmx[4];
    {
        const int bb = t >> 6, l = t & 63;
        float a = fminf(bmn[bb * 128 + l], bmn[bb * 128 + 64 + l]);
        a = wmin64(a);
        float z = fmaxf(bmx[bb * 128 + l], bmx[bb * 128 + 64 + l]);
        z = wmax64(z);
        if (l == 0) { shmn[bb] = a; shmx[bb] = z; }
    }
    __syncthreads();

    // rescale all 16384 pixels (64 per thread, coalesced), loss partial
    float lsum = 0.f;
#pragma unroll 4
    for (int i = 0; i < 64; ++i) {
        int p = i * 256 + t;
        int bb = i >> 4;                         // uniform per i
        float mn  = shmn[bb];
        float mxa = shmx[bb] + 1e-5f;
        float r = (ob[p] - mn) / (mxa - mn);
        out[p] = r;
        lsum += fabsf(r - cam[p]);
    }
    __shared__ float red2[4];
    float ps = wsum(lsum);
    if ((t & 63) == 0) red2[t >> 6] = ps;
    __syncthreads();
    if (t == 0)
        out[BN] = ((red2[0] + red2[1]) + (red2[2] + red2[3])) * (1.f / (float)BN);
}

extern "C" void kernel_launch(void* const* d_in, const int* in_sizes, int n_in,
                              void* d_out, int out_size, void* d_ws, size_t ws_size,
                              hipStream_t stream) {
    const float* cam  = (const float*)d_in[0];   // (4,64,64)
    const float* feat = (const float*)d_in[1];   // (4,256,64,64)
    float* out = (float*)d_out;                  // [16384 ref][1 loss]
    float* ws  = (float*)d_ws;

    float* s      = ws;                   // 16384
    float* v_part = ws + 16384;           // 512*256 = 131072
    float* v      = ws + 147456;          // 1024
    float* ob     = ws + 148480;          // 16384
    float* bmn    = ws + 164864;          // 512
    float* bmx    = ws + 165376;          // 512
    unsigned int* cnt = (unsigned int*)(ws + 165888);

    k_norm_vpart<<<NBLK, 256, 0, stream>>>(cam, feat, s, v_part, cnt);
    k_vreduce   <<<B,    256, 0, stream>>>(v_part, v);
    k_out_final <<<NBLK, 256, 0, stream>>>(feat, s, v, cam, ob, bmn, bmx, out, cnt);
}